// Round 9
// baseline (147289.539 us; speedup 1.0000x reference)
//
#include <hip/hip_runtime.h>
#include <stdint.h>

#define NRES 2048
#define NIN  64
#define NOUT 64
#define BB   32
#define TT   1024
#define FSTRIDE 16   // ints between flags (64 B: own cache line)

typedef __attribute__((ext_vector_type(8))) short bf16x8;
typedef __attribute__((ext_vector_type(4))) float f32x4;

__device__ __forceinline__ float bf2f(uint16_t u) {
  union { uint32_t i; float f; } v; v.i = ((uint32_t)u) << 16; return v.f;
}
__device__ __forceinline__ uint16_t f2bf_rne(float f) {
  union { float f; uint32_t i; } v; v.f = f;
  uint32_t lsb = (v.i >> 16) & 1u;
  v.i += 0x7fffu + lsb;
  return (uint16_t)(v.i >> 16);
}
__device__ __forceinline__ short hi16(float f) {
  return (short)(__float_as_uint(f) >> 16);   // exact: inputs are bf16-representable
}
__device__ __forceinline__ bf16x8 pack8(float4 a, float4 b) {
  bf16x8 r;
  r[0] = hi16(a.x); r[1] = hi16(a.y); r[2] = hi16(a.z); r[3] = hi16(a.w);
  r[4] = hi16(b.x); r[5] = hi16(b.y); r[6] = hi16(b.z); r[7] = hi16(b.w);
  return r;
}

// seed y with b_out; zero h buffer A (hi+lo = 65536 u32) and flags (4096 ints)
__global__ __launch_bounds__(256) void esn_init(const float* __restrict__ b_out,
                                                float* __restrict__ y,
                                                uint32_t* __restrict__ hz,
                                                int* __restrict__ flags) {
  int idx = blockIdx.x * 256 + threadIdx.x;   // grid 8192 -> 2,097,152
  y[idx] = b_out[idx & 63];
  if (idx < 65536) hz[idx] = 0u;
  if (idx < 4096) flags[idx] = 0;
}

// Persistent cooperative kernel. 256 blocks x 1024 threads (16 waves).
// Block (rt, bh): rows [rt*16, rt*16+16), batches [bh*16, bh*16+16).
// Wave w owns K slice [w*128, w*128+128) -> W_res A-frags held in VGPRs for all steps.
__global__ __launch_bounds__(1024, 4) void esn_persist(
    const float* __restrict__ x,       // [32][1024][64] f32
    const float* __restrict__ W_in,    // [2048][64]
    const float* __restrict__ W_res,   // [2048][2048]
    const float* __restrict__ b_res,   // [2048]
    const float* __restrict__ W_out,   // [64][2048]
    uint16_t* __restrict__ hA_hi, uint16_t* __restrict__ hA_lo,   // [32][2048] bf16
    uint16_t* __restrict__ hB_hi, uint16_t* __restrict__ hB_lo,
    int* __restrict__ flags,           // 256 flags, FSTRIDE apart
    float* __restrict__ y)             // [32][1024][64] f32 (atomic accumulate)
{
  __shared__ float wos[NOUT][17];      // W_out[o][r0..r0+15]
  __shared__ float red[16][16][17];    // [wave][rowM][colB]
  __shared__ float hs[16][17];         // h_new f32 for readout

  const int tid = threadIdx.x;
  const int l   = tid & 63;
  const int w   = tid >> 6;            // 0..15
  const int bid = blockIdx.x;
  const int rt  = bid >> 1;            // 0..127 row tile
  const int bh  = bid & 1;             // batch half
  const int r0  = rt << 4;
  const int b0  = bh << 4;
  const int m16 = l & 15;
  const int kg  = l >> 4;              // 0..3

  { // stage W_out slice once
    int o = tid >> 4, m = tid & 15;
    wos[o][m] = W_out[(size_t)o * NRES + r0 + m];
  }

  // ---- hoist W_res A-fragments (held across all 1024 steps) ----
  bf16x8 A[4];
  {
    const float* ap = W_res + (size_t)(r0 + m16) * NRES + w * 128 + kg * 8;
#pragma unroll
    for (int c = 0; c < 4; ++c) {
      float4 a0 = *reinterpret_cast<const float4*>(ap + c * 32);
      float4 a1 = *reinterpret_cast<const float4*>(ap + c * 32 + 4);
      A[c] = pack8(a0, a1);
    }
  }
  bf16x8 AX = {};                      // W_in frag for waves 14/15
  if (w >= 14) {
    int d0 = (w - 14) * 32;
    const float* aip = W_in + (size_t)(r0 + m16) * NIN + d0 + kg * 8;
    AX = pack8(*reinterpret_cast<const float4*>(aip),
               *reinterpret_cast<const float4*>(aip + 4));
  }

  const int bat = b0 + m16;            // B-frag column = batch
  const size_t hoff = (size_t)bat * NRES + w * 128 + kg * 8;
  const float* xbase = x + (size_t)bat * (TT * NIN) + (w >= 14 ? (w - 14) * 32 : 0) + kg * 8;

  const uint16_t* rh = hA_hi; const uint16_t* rl = hA_lo;   // read buffers (step 0)
  uint16_t* wh = hB_hi; uint16_t* wl = hB_lo;               // write buffers
  const int myflag = bid * FSTRIDE;

  __syncthreads();                     // wos ready

  for (int t = 0; t < TT; ++t) {
    // ---- MFMA phase: 4 chunks of K=32, hi+lo ----
    f32x4 acc0 = {0.f,0.f,0.f,0.f};
    f32x4 acc1 = {0.f,0.f,0.f,0.f};
    bf16x8 bh8[4], bl8[4];
#pragma unroll
    for (int c = 0; c < 4; ++c) {
      bh8[c] = *reinterpret_cast<const bf16x8*>(rh + hoff + c * 32);
      bl8[c] = *reinterpret_cast<const bf16x8*>(rl + hoff + c * 32);
    }
    acc0 = __builtin_amdgcn_mfma_f32_16x16x32_bf16(A[0], bh8[0], acc0, 0, 0, 0);
    acc1 = __builtin_amdgcn_mfma_f32_16x16x32_bf16(A[1], bh8[1], acc1, 0, 0, 0);
    acc0 = __builtin_amdgcn_mfma_f32_16x16x32_bf16(A[0], bl8[0], acc0, 0, 0, 0);
    acc1 = __builtin_amdgcn_mfma_f32_16x16x32_bf16(A[1], bl8[1], acc1, 0, 0, 0);
    acc0 = __builtin_amdgcn_mfma_f32_16x16x32_bf16(A[2], bh8[2], acc0, 0, 0, 0);
    acc1 = __builtin_amdgcn_mfma_f32_16x16x32_bf16(A[3], bh8[3], acc1, 0, 0, 0);
    acc0 = __builtin_amdgcn_mfma_f32_16x16x32_bf16(A[2], bl8[2], acc0, 0, 0, 0);
    acc1 = __builtin_amdgcn_mfma_f32_16x16x32_bf16(A[3], bl8[3], acc1, 0, 0, 0);

    if (w >= 14) {                     // U = W_in @ x_t contribution
      const float* xp = xbase + (size_t)t * NIN;
      bf16x8 xb = pack8(*reinterpret_cast<const float4*>(xp),
                        *reinterpret_cast<const float4*>(xp + 4));
      acc0 = __builtin_amdgcn_mfma_f32_16x16x32_bf16(AX, xb, acc0, 0, 0, 0);
    }

    f32x4 s = acc0 + acc1;
#pragma unroll
    for (int j = 0; j < 4; ++j) red[w][kg * 4 + j][m16] = s[j];  // D: row=(l>>4)*4+j, col=l&15
    __syncthreads();

    if (tid < 256) {                   // reduce 16 waves, tanh, split hi/lo, store
      int rowM = tid & 15, colB = tid >> 4;
      float ss = b_res[r0 + rowM];
#pragma unroll
      for (int ww = 0; ww < 16; ++ww) ss += red[ww][rowM][colB];
      float h = tanhf(ss);
      uint16_t hhv = f2bf_rne(h);
      float rem = h - bf2f(hhv);
      size_t off = (size_t)(b0 + colB) * NRES + r0 + rowM;
      wh[off] = hhv;
      wl[off] = f2bf_rne(rem);
      hs[rowM][colB] = h;
    }
    __threadfence();                   // release: h stores -> device visible
    __syncthreads();                   // all stores + fences done; hs ready

    if (tid == 0)
      __hip_atomic_store(&flags[myflag], t + 1, __ATOMIC_RELEASE, __HIP_MEMORY_SCOPE_AGENT);

    { // fused readout (fire-and-forget atomics, overlaps the spin)
      int o = tid >> 4, bb = tid & 15;
      float d = 0.f;
#pragma unroll
      for (int m = 0; m < 16; ++m) d += wos[o][m] * hs[m][bb];
      atomicAdd(y + (size_t)(b0 + bb) * (TT * NOUT) + (size_t)t * NOUT + o, d);
    }

    if (w == 0) {                      // wave 0 spins on all 256 flags
      int target = t + 1;
      int f0, f1, f2, f3;
      do {
        f0 = __hip_atomic_load(&flags[(l)       * FSTRIDE], __ATOMIC_RELAXED, __HIP_MEMORY_SCOPE_AGENT);
        f1 = __hip_atomic_load(&flags[(l +  64) * FSTRIDE], __ATOMIC_RELAXED, __HIP_MEMORY_SCOPE_AGENT);
        f2 = __hip_atomic_load(&flags[(l + 128) * FSTRIDE], __ATOMIC_RELAXED, __HIP_MEMORY_SCOPE_AGENT);
        f3 = __hip_atomic_load(&flags[(l + 192) * FSTRIDE], __ATOMIC_RELAXED, __HIP_MEMORY_SCOPE_AGENT);
      } while (__any((min(min(f0, f1), min(f2, f3))) < target));
    }
    __threadfence();                   // acquire: invalidate stale cached h
    __syncthreads();                   // release all waves into next step

    const uint16_t* trh = rh; const uint16_t* trl = rl;     // swap ping-pong
    rh = wh; rl = wl;
    wh = (uint16_t*)trh; wl = (uint16_t*)trl;
  }
}

// ---------------- legacy dense-VALU fallback (tiny ws) ----------------------
__global__ __launch_bounds__(256) void legacy_init(const float* __restrict__ b_out,
                                                   float* __restrict__ y,
                                                   float* __restrict__ h0) {
  int idx = blockIdx.x * 256 + threadIdx.x;
  y[idx] = b_out[idx & 63];
  if (idx < NRES * BB) h0[idx] = 0.0f;
}

__global__ __launch_bounds__(256) void legacy_step(
    const float* __restrict__ x, const float* __restrict__ W_in,
    const float* __restrict__ W_res, const float* __restrict__ b_res,
    const float* __restrict__ W_out, const float* __restrict__ h_in,
    float* __restrict__ h_out, float* __restrict__ y, int t)
{
  __shared__ float xs[BB][NIN + 1];
  __shared__ float hsL[8][BB + 1];
  __shared__ float wosL[NOUT][9];
  int tid = threadIdx.x;
  int r0  = blockIdx.x << 3;
  {
    int i = tid * 8, b = i >> 6, d = i & 63;
    const float* src = x + (size_t)b * (TT * NIN) + (size_t)t * NIN + d;
    float4 v0 = *reinterpret_cast<const float4*>(src);
    float4 v1 = *reinterpret_cast<const float4*>(src + 4);
    xs[b][d + 0] = v0.x; xs[b][d + 1] = v0.y; xs[b][d + 2] = v0.z; xs[b][d + 3] = v0.w;
    xs[b][d + 4] = v1.x; xs[b][d + 5] = v1.y; xs[b][d + 6] = v1.z; xs[b][d + 7] = v1.w;
  }
  {
    int o = tid >> 2, jj = (tid & 3) * 2;
    float2 w2 = *reinterpret_cast<const float2*>(W_out + (size_t)o * NRES + r0 + jj);
    wosL[o][jj] = w2.x; wosL[o][jj + 1] = w2.y;
  }
  __syncthreads();
  int b = tid & 31, rr = tid >> 5, r = r0 + rr;
  float acc = b_res[r];
  const float* wi = W_in + (size_t)r * NIN;
#pragma unroll
  for (int d = 0; d < NIN; d += 8) {
    float4 w0 = *reinterpret_cast<const float4*>(wi + d);
    float4 w1 = *reinterpret_cast<const float4*>(wi + d + 4);
    acc += w0.x * xs[b][d + 0] + w0.y * xs[b][d + 1] + w0.z * xs[b][d + 2] + w0.w * xs[b][d + 3] +
           w1.x * xs[b][d + 4] + w1.y * xs[b][d + 5] + w1.z * xs[b][d + 6] + w1.w * xs[b][d + 7];
  }
  const float* wr = W_res + (size_t)r * NRES;
  const float* hbp = h_in + b;
  for (int k = 0; k < NRES; k += 8) {
    float4 w0 = *reinterpret_cast<const float4*>(wr + k);
    float4 w1 = *reinterpret_cast<const float4*>(wr + k + 4);
    acc += w0.x * hbp[(size_t)(k + 0) * BB] + w0.y * hbp[(size_t)(k + 1) * BB] +
           w0.z * hbp[(size_t)(k + 2) * BB] + w0.w * hbp[(size_t)(k + 3) * BB] +
           w1.x * hbp[(size_t)(k + 4) * BB] + w1.y * hbp[(size_t)(k + 5) * BB] +
           w1.z * hbp[(size_t)(k + 6) * BB] + w1.w * hbp[(size_t)(k + 7) * BB];
  }
  float h = tanhf(acc);
  h_out[r * BB + b] = h;
  hsL[rr][b] = h;
  __syncthreads();
  float h8[8];
#pragma unroll
  for (int j = 0; j < 8; ++j) h8[j] = hsL[j][b];
  float* yrow = y + (size_t)b * (TT * NOUT) + (size_t)t * NOUT;
#pragma unroll
  for (int oo = 0; oo < 8; ++oo) {
    int o = oo * 8 + rr;
    float p = 0.f;
#pragma unroll
    for (int j = 0; j < 8; ++j) p += h8[j] * wosL[o][j];
    atomicAdd(yrow + o, p);
  }
}

// ---------------------------------------------------------------------------
extern "C" void kernel_launch(void* const* d_in, const int* in_sizes, int n_in,
                              void* d_out, int out_size, void* d_ws, size_t ws_size,
                              hipStream_t stream) {
  const float* p_x = 0; const float* p_Win = 0; const float* p_Wres = 0;
  const float* p_bres = 0; const float* p_Wout = 0; const float* p_bout = 0;
  for (int i = 0; i < n_in; ++i) {
    const float* p = (const float*)d_in[i];
    switch (in_sizes[i]) {
      case 2097152: p_x = p; break;
      case 4194304: p_Wres = p; break;
      case 2048:    p_bres = p; break;
      case 64:      p_bout = p; break;
      case 131072:  if (!p_Win) p_Win = p; else p_Wout = p; break;  // dict order: W_in first
      default: break;
    }
  }
  if (!p_x || !p_Win || !p_Wres || !p_bres || !p_Wout || !p_bout) {
    p_x    = (const float*)d_in[0];
    p_Win  = (const float*)d_in[1];
    p_Wres = (const float*)d_in[2];
    p_bres = (const float*)d_in[3];
    p_Wout = (const float*)d_in[4];
    p_bout = (const float*)d_in[5];
  }

  float* y = (float*)d_out;

  // ws: [hA_hi 128K][hA_lo 128K][hB_hi 128K][hB_lo 128K][flags 16K] = 544 KiB
  if (ws_size >= 557056) {
    uint16_t* hA_hi = (uint16_t*)d_ws;
    uint16_t* hA_lo = (uint16_t*)((char*)d_ws + 131072);
    uint16_t* hB_hi = (uint16_t*)((char*)d_ws + 262144);
    uint16_t* hB_lo = (uint16_t*)((char*)d_ws + 393216);
    int*      flags = (int*)((char*)d_ws + 524288);

    esn_init<<<dim3(8192), dim3(256), 0, stream>>>(p_bout, y, (uint32_t*)d_ws, flags);

    void* args[] = { (void*)&p_x, (void*)&p_Win, (void*)&p_Wres, (void*)&p_bres,
                     (void*)&p_Wout, (void*)&hA_hi, (void*)&hA_lo, (void*)&hB_hi,
                     (void*)&hB_lo, (void*)&flags, (void*)&y };
    hipLaunchCooperativeKernel((void*)esn_persist, dim3(256), dim3(1024),
                               args, 0, stream);
  } else {
    float* h0 = (float*)d_ws;
    float* h1 = (float*)((char*)d_ws + 262144);
    legacy_init<<<dim3(8192), dim3(256), 0, stream>>>(p_bout, y, h0);
    float* ha = h0; float* hb = h1;
    for (int t = 0; t < TT; ++t) {
      legacy_step<<<dim3(256), dim3(256), 0, stream>>>(p_x, p_Win, p_Wres, p_bres, p_Wout,
                                                       ha, hb, y, t);
      float* tmp = ha; ha = hb; hb = tmp;
    }
  }
}